// Round 14
// baseline (316.729 us; speedup 1.0000x reference)
//
#include <hip/hip_runtime.h>
#include <hip/hip_bf16.h>

#define NNODES 100000
#define NEDGES 1600000
#define DF 128
#define NGRAPH 256
#define SCAN_CHUNK 2048
#define NB_SCAN ((NNODES + SCAN_CHUNK - 1) / SCAN_CHUNK)

#define BUCKET_SHIFT 7
#define BUCKET_NODES 128
#define NBUCK ((NNODES + BUCKET_NODES - 1) / BUCKET_NODES)   // 782
#define SCHUNK 8192
#define NBLK2 ((NEDGES + SCHUNK - 1) / SCHUNK)               // 196

typedef __attribute__((ext_vector_type(8))) short short8;
typedef __attribute__((ext_vector_type(4))) float f32x4;

// ---------------- pass A: per-block bucket histogram -> cnt[blk][NBUCK] (no atomics) --
__global__ __launch_bounds__(1024) void hist2(const int* __restrict__ dst,
                                              int* __restrict__ cnt, int E) {
    __shared__ int h[NBUCK];
    for (int i = threadIdx.x; i < NBUCK; i += 1024) h[i] = 0;
    __syncthreads();
    int base = blockIdx.x * SCHUNK;
    #pragma unroll
    for (int j = 0; j < 8; j++) {
        int e = base + threadIdx.x + j * 1024;
        if (e < E) atomicAdd(&h[dst[e] >> BUCKET_SHIFT], 1);
    }
    __syncthreads();
    for (int i = threadIdx.x; i < NBUCK; i += 1024)
        cnt[blockIdx.x * NBUCK + i] = h[i];
}

// ---------------- per-bucket exclusive scan over blocks -> bstart[blk][b], btot[b] ----
__global__ void bscan1(const int* __restrict__ cnt, int* __restrict__ bstart,
                       int* __restrict__ btot) {
    int b = blockIdx.x;      // one 64-thread wave per bucket
    int l = threadIdx.x;
    int vals[4];
    int s = 0;
    #pragma unroll
    for (int i = 0; i < 4; i++) {
        int blk = l * 4 + i;
        vals[i] = (blk < NBLK2) ? cnt[blk * NBUCK + b] : 0;
        s += vals[i];
    }
    int pre = s;
    for (int off = 1; off < 64; off <<= 1) {
        int t = __shfl_up(pre, off, 64);
        if (l >= off) pre += t;
    }
    pre -= s;  // exclusive prefix of this lane's group
    int run = pre;
    #pragma unroll
    for (int i = 0; i < 4; i++) {
        int blk = l * 4 + i;
        if (blk < NBLK2) { bstart[blk * NBUCK + b] = run; run += vals[i]; }
    }
    if (l == 63) btot[b] = pre + s;
}

// ---------------- scan bucket totals -> segoff[0..NBUCK] ----------------
__global__ void segscan2(const int* __restrict__ btot, int* __restrict__ segoff) {
    __shared__ int lds[256];
    int t = threadIdx.x;
    int b0 = t * 4;
    int v[4];
    int s = 0;
    #pragma unroll
    for (int i = 0; i < 4; i++) { int b = b0 + i; v[i] = (b < NBUCK) ? btot[b] : 0; s += v[i]; }
    lds[t] = s;
    __syncthreads();
    for (int off = 1; off < 256; off <<= 1) {
        int x = lds[t];
        int a = (t >= off) ? lds[t - off] : 0;
        __syncthreads();
        lds[t] = x + a;
        __syncthreads();
    }
    int run = lds[t] - s;
    #pragma unroll
    for (int i = 0; i < 4; i++) {
        int b = b0 + i;
        if (b < NBUCK) { segoff[b] = run; run += v[i]; }
    }
    if (t == 255) segoff[NBUCK] = lds[255];
}

// ---------------- pass B: LDS counting-sort scatter, burst coalesced writes ----------
__global__ __launch_bounds__(1024) void scatter2(const int* __restrict__ src,
                                                 const int* __restrict__ dst,
                                                 const int* __restrict__ bstart,
                                                 const int* __restrict__ segoff,
                                                 unsigned int* __restrict__ stage, int E) {
    __shared__ unsigned int rec[SCHUNK];     // 32 KB sorted records
    __shared__ unsigned short bid[SCHUNK];   // 16 KB bucket id per slot
    __shared__ int hs[1024];                 // per-bucket counts
    __shared__ int wsum[16];
    __shared__ int cur[NBUCK];               // local cursors
    __shared__ int delta[NBUCK];             // global dest - local slot
    __shared__ int nrec_s;
    int tid = threadIdx.x, lane = tid & 63, wid = tid >> 6;
    int base = blockIdx.x * SCHUNK;
    hs[tid] = 0;
    __syncthreads();
    int myd[8], mys[8];
    #pragma unroll
    for (int j = 0; j < 8; j++) {
        int e = base + tid + j * 1024;
        if (e < E) {
            myd[j] = dst[e];
            mys[j] = src[e];
            atomicAdd(&hs[myd[j] >> BUCKET_SHIFT], 1);
        } else myd[j] = -1;
    }
    __syncthreads();
    int cnt_t = hs[tid];
    // wave-level inclusive scan (no barriers), then cross-wave via LDS
    int pre = cnt_t;
    for (int off = 1; off < 64; off <<= 1) {
        int t = __shfl_up(pre, off, 64);
        if (lane >= off) pre += t;
    }
    if (lane == 63) wsum[wid] = pre;
    __syncthreads();
    if (tid == 0) {
        int r = 0;
        #pragma unroll
        for (int i = 0; i < 16; i++) { int t = wsum[i]; wsum[i] = r; r += t; }
        nrec_s = r;
    }
    __syncthreads();
    int excl = pre - cnt_t + wsum[wid];
    if (tid < NBUCK) {
        cur[tid] = excl;
        delta[tid] = segoff[tid] + bstart[blockIdx.x * NBUCK + tid] - excl;
    }
    __syncthreads();
    #pragma unroll
    for (int j = 0; j < 8; j++) {
        if (myd[j] >= 0) {
            int b = myd[j] >> BUCKET_SHIFT;
            int p = atomicAdd(&cur[b], 1);
            rec[p] = (unsigned int)mys[j] | (((unsigned int)myd[j] & 127u) << 17);
            bid[p] = (unsigned short)b;
        }
    }
    __syncthreads();
    int nrec = nrec_s;
    for (int i = tid; i < nrec; i += 1024)
        stage[delta[bid[i]] + i] = rec[i];
}

// ---------------- pass C1: per-bucket LDS histogram -> deg (streaming writes) --------
__global__ void bucket_deg(const unsigned int* __restrict__ stage, const int* __restrict__ segoff,
                           int* __restrict__ deg, int n) {
    __shared__ int h[BUCKET_NODES];
    int b = blockIdx.x;
    if (threadIdx.x < BUCKET_NODES) h[threadIdx.x] = 0;
    __syncthreads();
    int s0 = segoff[b], s1 = segoff[b + 1];
    for (int i = s0 + threadIdx.x; i < s1; i += 256)
        atomicAdd(&h[(stage[i] >> 17) & 127u], 1);
    __syncthreads();
    int v = b * BUCKET_NODES + threadIdx.x;
    if (threadIdx.x < BUCKET_NODES && v < n) deg[v] = h[threadIdx.x];
}

// ---------------- hierarchical scan of (deg[v]+1); also emits dinv ----------------
__global__ void scan1_kernel(const int* __restrict__ deg, int* __restrict__ psum,
                             float* __restrict__ dinv, int n) {
    __shared__ int lds[256];
    int t = threadIdx.x;
    int base = blockIdx.x * SCAN_CHUNK + t * 8;
    int s = 0;
    #pragma unroll
    for (int i = 0; i < 8; i++) {
        int idx = base + i;
        if (idx < n) {
            int d = deg[idx];
            dinv[idx] = rsqrtf((float)d + 1.0f);
            s += d + 1;
        }
    }
    lds[t] = s;
    __syncthreads();
    for (int off = 128; off > 0; off >>= 1) {
        if (t < off) lds[t] += lds[t + off];
        __syncthreads();
    }
    if (t == 0) psum[blockIdx.x] = lds[0];
}

__global__ void scan2_kernel(int* __restrict__ psum, int* __restrict__ offs, int nb, int n) {
    __shared__ int lds[64];
    int t = threadIdx.x;  // 64 threads
    int v = (t < nb) ? psum[t] : 0;
    lds[t] = v;
    __syncthreads();
    for (int off = 1; off < 64; off <<= 1) {
        int x = lds[t];
        int add = (t >= off) ? lds[t - off] : 0;
        __syncthreads();
        lds[t] = x + add;
        __syncthreads();
    }
    if (t < nb) psum[t] = lds[t] - v;  // exclusive prefix of block sums
    if (t == 63) offs[n] = lds[63];    // grand total
}

// scan3: offs[] only
__global__ void scan3_kernel(const int* __restrict__ deg, const int* __restrict__ psum,
                             int* __restrict__ offs, int n) {
    __shared__ int lds[256];
    int t = threadIdx.x;
    int base = blockIdx.x * SCAN_CHUNK + t * 8;
    int dv[8];
    int s = 0;
    #pragma unroll
    for (int i = 0; i < 8; i++) {
        int idx = base + i;
        dv[i] = (idx < n) ? deg[idx] + 1 : 0;
        s += dv[i];
    }
    lds[t] = s;
    __syncthreads();
    for (int off = 1; off < 256; off <<= 1) {
        int x = lds[t];
        int add = (t >= off) ? lds[t - off] : 0;
        __syncthreads();
        lds[t] = x + add;
        __syncthreads();
    }
    int run = psum[blockIdx.x] + lds[t] - s;
    #pragma unroll
    for (int i = 0; i < 8; i++) {
        int idx = base + i;
        if (idx < n) { offs[idx] = run; run += dv[i]; }
    }
}

// ---------------- pass C2: place csrc (self + edges) within bucket's contiguous region
__global__ void bucket_place(const unsigned int* __restrict__ stage, const int* __restrict__ segoff,
                             const int* __restrict__ offs, int* __restrict__ csrc, int n) {
    __shared__ int cur[BUCKET_NODES];
    int b = blockIdx.x;
    int v = b * BUCKET_NODES + threadIdx.x;
    if (threadIdx.x < BUCKET_NODES && v < n) {
        int o = offs[v];
        csrc[o] = v;                 // slot 0 = self loop
        cur[threadIdx.x] = o + 1;
    }
    __syncthreads();
    int s0 = segoff[b], s1 = segoff[b + 1];
    for (int i = s0 + threadIdx.x; i < s1; i += 256) {
        unsigned int r = stage[i];
        int pos = atomicAdd(&cur[(r >> 17) & 127u], 1);
        csrc[pos] = (int)(r & 0x1ffffu);
    }
}

// RNE pack: two f32 -> bf16x2 (lo = a, hi = b)
__device__ __forceinline__ unsigned int pack_bf16x2(float a, float b) {
    unsigned int ua = __float_as_uint(a);
    unsigned int ub = __float_as_uint(b);
    ua += 0x7fffu + ((ua >> 16) & 1u);
    ub += 0x7fffu + ((ub >> 16) & 1u);
    return (ua >> 16) | (ub & 0xffff0000u);
}

// split f32 -> (hi bf16, lo bf16): w ~= hi + lo, error ~2^-17 relative
__device__ __forceinline__ void split_bf16(float w, unsigned short& h, unsigned short& l) {
    unsigned int uw = __float_as_uint(w);
    unsigned int hb = uw + 0x7fffu + ((uw >> 16) & 1u);
    h = (unsigned short)(hb >> 16);
    float rem = w - __uint_as_float((unsigned int)h << 16);
    unsigned int ur = __float_as_uint(rem);
    unsigned int lb = ur + 0x7fffu + ((ur >> 16) & 1u);
    l = (unsigned short)(lb >> 16);
}

// ---------------- W prep (both weights in one launch): frag-major split-bf16 ----------
__global__ void wprep2(const float* __restrict__ W1, const float* __restrict__ W2,
                       unsigned short* __restrict__ Wh1, unsigned short* __restrict__ Wl1,
                       unsigned short* __restrict__ Wh2, unsigned short* __restrict__ Wl2) {
    int gidx = blockIdx.x * 256 + threadIdx.x;  // 0..4095
    int which = gidx >> 11;
    int id = gidx & 2047;
    const float* W = which ? W2 : W1;
    unsigned short* Wh = which ? Wh2 : Wh1;
    unsigned short* Wl = which ? Wl2 : Wl1;
    int lane = id & 63, tq = id >> 6;
    int t = tq >> 2, q = tq & 3;
    int n = 16 * t + (lane & 15);
    int kbase = 32 * q + 8 * (lane >> 4);
    unsigned short h[8], l[8];
    #pragma unroll
    for (int i = 0; i < 8; i++) {
        split_bf16(W[(kbase + i) * DF + n], h[i], l[i]);
    }
    uint4 hv, lv;
    hv.x = h[0] | ((unsigned int)h[1] << 16); hv.y = h[2] | ((unsigned int)h[3] << 16);
    hv.z = h[4] | ((unsigned int)h[5] << 16); hv.w = h[6] | ((unsigned int)h[7] << 16);
    lv.x = l[0] | ((unsigned int)l[1] << 16); lv.y = l[2] | ((unsigned int)l[3] << 16);
    lv.z = l[4] | ((unsigned int)l[5] << 16); lv.w = l[6] | ((unsigned int)l[7] << 16);
    ((uint4*)Wh)[id] = hv;
    ((uint4*)Wl)[id] = lv;
}

// ---------------- MFMA GEMM: C_bf16[n,128] = dinv[n] * (A[n,128] @ W[128,128]) --------
template <int ABF16>
__global__ void gemm_mfma(const void* __restrict__ Ap, const unsigned short* __restrict__ Wh,
                          const unsigned short* __restrict__ Wl, const float* __restrict__ dinv,
                          unsigned int* __restrict__ C, int nrows) {
    int tid = threadIdx.x;
    int wv = tid >> 6, lane = tid & 63;
    int c16 = lane & 15, g = lane >> 4;
    int row = blockIdx.x * 64 + wv * 16 + c16;
    int rowc = min(row, nrows - 1);
    const short8* Wh8 = (const short8*)Wh;
    const short8* Wl8 = (const short8*)Wl;
    f32x4 acc[8];
    #pragma unroll
    for (int t = 0; t < 8; t++) acc[t] = (f32x4){0.f, 0.f, 0.f, 0.f};
    #pragma unroll
    for (int q = 0; q < 4; q++) {
        short8 ah, al;
        if (ABF16) {
            ah = ((const short8*)Ap)[(size_t)rowc * 16 + q * 4 + g];
        } else {
            const float4* A4 = (const float4*)Ap;
            float4 a0 = A4[(size_t)rowc * 32 + q * 8 + g * 2];
            float4 a1 = A4[(size_t)rowc * 32 + q * 8 + g * 2 + 1];
            float av[8] = {a0.x, a0.y, a0.z, a0.w, a1.x, a1.y, a1.z, a1.w};
            #pragma unroll
            for (int i = 0; i < 8; i++) {
                unsigned short hs, ls;
                split_bf16(av[i], hs, ls);
                ah[i] = (short)hs;
                al[i] = (short)ls;
            }
        }
        #pragma unroll
        for (int t = 0; t < 8; t++) {
            short8 wh = Wh8[(t * 4 + q) * 64 + lane];
            short8 wl = Wl8[(t * 4 + q) * 64 + lane];
            acc[t] = __builtin_amdgcn_mfma_f32_16x16x32_bf16(wh, ah, acc[t], 0, 0, 0);
            if (!ABF16) acc[t] = __builtin_amdgcn_mfma_f32_16x16x32_bf16(wh, al, acc[t], 0, 0, 0);
            acc[t] = __builtin_amdgcn_mfma_f32_16x16x32_bf16(wl, ah, acc[t], 0, 0, 0);
        }
    }
    if (row < nrows) {
        float dvr = dinv[row];
        uint2* C2 = (uint2*)C;
        #pragma unroll
        for (int t = 0; t < 8; t++) {
            uint2 w;
            w.x = pack_bf16x2(acc[t][0] * dvr, acc[t][1] * dvr);
            w.y = pack_bf16x2(acc[t][2] * dvr, acc[t][3] * dvr);
            C2[(size_t)row * 32 + t * 4 + g] = w;
        }
    }
}

// ---------------- gather core (R12 structure): 4B/lane, one 256B row per instruction,
// 8 independent gathers in flight. Lane owns feats {2*lane, 2*lane+1}.
__device__ __forceinline__ float2 gather_rows(const int* __restrict__ roff,
                                              const int* __restrict__ csrc,
                                              const unsigned int* __restrict__ Hb,
                                              size_t v, int lane) {
    int b = roff[v], e = roff[v + 1];
    float2 acc = {0.f, 0.f};
    for (int base = b; base < e; base += 64) {
        int idx = base + lane;
        if (idx >= e) idx = e - 1;       // clamped dup, never consumed
        int rec = csrc[idx];             // one coalesced 256B record load
        int kmax = min(64, e - base);
        int k = 0;
        for (; k + 8 <= kmax; k += 8) {
            unsigned int u[8];
            #pragma unroll
            for (int j = 0; j < 8; j++) {
                int s = __shfl(rec, k + j, 64);
                u[j] = Hb[(size_t)s * 64 + lane];      // 256B row gather
            }
            #pragma unroll
            for (int j = 0; j < 8; j++) {
                acc.x += __uint_as_float(u[j] << 16);
                acc.y += __uint_as_float(u[j] & 0xffff0000u);
            }
        }
        for (; k < kmax; k++) {
            int s0 = __shfl(rec, k, 64);
            unsigned int u0 = Hb[(size_t)s0 * 64 + lane];
            acc.x += __uint_as_float(u0 << 16);
            acc.y += __uint_as_float(u0 & 0xffff0000u);
        }
    }
    return acc;
}

// ---------------- agg layer 1: out bf16 with bias+relu ----------------
__global__ void agg_mid(const int* __restrict__ roff, const int* __restrict__ csrc,
                        const float* __restrict__ dinv, const unsigned int* __restrict__ Hb,
                        const float* __restrict__ bias, unsigned int* __restrict__ Out) {
    int tid = threadIdx.x, wv = tid >> 6, lane = tid & 63;
    size_t v = (size_t)blockIdx.x * 4 + wv;
    float2 acc = gather_rows(roff, csrc, Hb, v, lane);
    float dvv = dinv[v];
    float2 bb = ((const float2*)bias)[lane];
    float a0 = fmaxf(acc.x * dvv + bb.x, 0.f);
    float a1 = fmaxf(acc.y * dvv + bb.y, 0.f);
    Out[v * 64 + lane] = pack_bf16x2(a0, a1);
}

// ---------------- agg layer 2 fused with mean-pool accumulation ----------------
__global__ void agg_pool(const int* __restrict__ roff, const int* __restrict__ csrc,
                         const float* __restrict__ dinv, const unsigned int* __restrict__ Hb,
                         const int* __restrict__ batch,
                         float* __restrict__ gsum, float* __restrict__ gcnt) {
    __shared__ float red[4][128];
    __shared__ int gid[4];
    __shared__ int same;
    int tid = threadIdx.x, wv = tid >> 6, lane = tid & 63;
    size_t v = (size_t)blockIdx.x * 4 + wv;
    float2 acc = gather_rows(roff, csrc, Hb, v, lane);
    float dvv = dinv[v];
    acc.x *= dvv; acc.y *= dvv;
    *(float2*)&red[wv][lane * 2] = acc;
    if (lane == 0) gid[wv] = batch[v];
    __syncthreads();
    if (tid == 0) same = (gid[0] == gid[1]) && (gid[1] == gid[2]) && (gid[2] == gid[3]);
    __syncthreads();
    if (same) {
        if (wv == 0) {
            #pragma unroll
            for (int r = 0; r < 2; r++) {
                int f = lane + r * 64;
                atomicAdd(&gsum[gid[0] * DF + f], red[0][f] + red[1][f] + red[2][f] + red[3][f]);
            }
            if (lane == 0) atomicAdd(&gcnt[gid[0]], 4.0f);
        }
    } else {
        #pragma unroll
        for (int r = 0; r < 2; r++) {
            int f = lane + r * 64;
            atomicAdd(&gsum[gid[wv] * DF + f], red[wv][f]);
        }
        if (lane == 0) atomicAdd(&gcnt[gid[wv]], 1.0f);
    }
}

// ---------------- final: out[g] = dot(gsum[g]/cnt + b2, Wm) + bm ----------------
__global__ void final_kernel(const float* __restrict__ gsum, const float* __restrict__ gcnt,
                             const float* __restrict__ b2, const float* __restrict__ Wm,
                             const float* __restrict__ bm, float* __restrict__ out) {
    __shared__ float red[2];
    int g = blockIdx.x, d = threadIdx.x;
    float cnt = fmaxf(gcnt[g], 1.0f);
    float v = (gsum[g * DF + d] / cnt + b2[d]) * Wm[d];
    for (int off = 32; off > 0; off >>= 1) v += __shfl_down(v, off, 64);
    if ((d & 63) == 0) red[d >> 6] = v;
    __syncthreads();
    if (d == 0) out[g] = red[0] + red[1] + bm[0];
}

extern "C" void kernel_launch(void* const* d_in, const int* in_sizes, int n_in,
                              void* d_out, int out_size, void* d_ws, size_t ws_size,
                              hipStream_t stream) {
    const float* x   = (const float*)d_in[0];
    const int*   ei  = (const int*)d_in[1];   // [2, E] flat: first E = src, next E = dst
    const int*   bat = (const int*)d_in[2];
    const float* W1  = (const float*)d_in[3];
    const float* b1  = (const float*)d_in[4];
    const float* W2  = (const float*)d_in[5];
    const float* b2  = (const float*)d_in[6];
    const float* Wm  = (const float*)d_in[7];
    const float* bm  = (const float*)d_in[8];
    float* out = (float*)d_out;

    const int N = NNODES, E = NEDGES, G = NGRAPH;
    const int* src = ei;
    const int* dst = ei + E;

    // workspace carve
    char* base = (char*)d_ws;
    size_t o = 0;
    auto alloc = [&](size_t bytes) { size_t p = o; o = (o + bytes + 255) & ~(size_t)255; return p; };
    int*   deg    = (int*)(base + alloc((size_t)N * 4));
    int*   offs   = (int*)(base + alloc((size_t)(N + 1) * 4));
    float* dinv   = (float*)(base + alloc((size_t)N * 4));
    int*   psum   = (int*)(base + alloc((size_t)NB_SCAN * 4));
    int*   cnt    = (int*)(base + alloc((size_t)NBLK2 * NBUCK * 4));
    int*   bstart = (int*)(base + alloc((size_t)NBLK2 * NBUCK * 4));
    int*   btot   = (int*)(base + alloc((size_t)NBUCK * 4));
    int*   segoff = (int*)(base + alloc((size_t)(NBUCK + 1) * 4));
    unsigned int* stage = (unsigned int*)(base + alloc((size_t)E * 4));
    int*   csrc   = (int*)(base + alloc((size_t)(E + N) * 4));
    unsigned int* bufH  = (unsigned int*)(base + alloc((size_t)N * DF * 2));  // bf16 H (dinv-scaled)
    unsigned int* bufA16 = (unsigned int*)(base + alloc((size_t)N * DF * 2)); // bf16 layer-1 output
    float* gsum   = (float*)(base + alloc((size_t)G * DF * 4));
    float* gcnt   = (float*)(base + alloc((size_t)G * 4));
    unsigned short* wh1 = (unsigned short*)(base + alloc(2048 * 16));
    unsigned short* wl1 = (unsigned short*)(base + alloc(2048 * 16));
    unsigned short* wh2 = (unsigned short*)(base + alloc(2048 * 16));
    unsigned short* wl2 = (unsigned short*)(base + alloc(2048 * 16));
    (void)ws_size;

    hipMemsetAsync(gsum, 0, (size_t)G * DF * 4, stream);
    hipMemsetAsync(gcnt, 0, (size_t)G * 4, stream);

    // atomic-free binned CSR build
    hist2<<<NBLK2, 1024, 0, stream>>>(dst, cnt, E);
    bscan1<<<NBUCK, 64, 0, stream>>>(cnt, bstart, btot);
    segscan2<<<1, 256, 0, stream>>>(btot, segoff);
    scatter2<<<NBLK2, 1024, 0, stream>>>(src, dst, bstart, segoff, stage, E);
    bucket_deg<<<NBUCK, 256, 0, stream>>>(stage, segoff, deg, N);
    scan1_kernel<<<NB_SCAN, 256, 0, stream>>>(deg, psum, dinv, N);
    scan2_kernel<<<1, 64, 0, stream>>>(psum, offs, NB_SCAN, N);
    scan3_kernel<<<NB_SCAN, 256, 0, stream>>>(deg, psum, offs, N);
    bucket_place<<<NBUCK, 256, 0, stream>>>(stage, segoff, offs, csrc, N);

    // W prep (both layers, one launch)
    wprep2<<<16, 256, 0, stream>>>(W1, W2, wh1, wl1, wh2, wl2);

    // layer 1: bufH = bf16(dinv .* (x @ W1)) ; bufA16 = bf16(relu(dinv[v]*sum + b1))
    gemm_mfma<0><<<(N + 63) / 64, 256, 0, stream>>>(x, wh1, wl1, dinv, bufH, N);
    agg_mid<<<N / 4, 256, 0, stream>>>(offs, csrc, dinv, bufH, b1, bufA16);

    // layer 2: bufH = bf16(dinv .* (bufA16 @ W2)) ; fused agg + mean-pool accumulate
    gemm_mfma<1><<<(N + 63) / 64, 256, 0, stream>>>(bufA16, wh2, wl2, dinv, bufH, N);
    agg_pool<<<N / 4, 256, 0, stream>>>(offs, csrc, dinv, bufH, bat, gsum, gcnt);

    // final
    final_kernel<<<G, 128, 0, stream>>>(gsum, gcnt, b2, Wm, bm, out);
}

// Round 15
// 280.534 us; speedup vs baseline: 1.1290x; 1.1290x over previous
//
#include <hip/hip_runtime.h>
#include <hip/hip_bf16.h>

#define NNODES 100000
#define NEDGES 1600000
#define DF 128
#define NGRAPH 256
#define SCAN_CHUNK 2048
#define NB_SCAN ((NNODES + SCAN_CHUNK - 1) / SCAN_CHUNK)

#define BUCKET_SHIFT 7
#define BUCKET_NODES 128
#define NBUCK ((NNODES + BUCKET_NODES - 1) / BUCKET_NODES)   // 782
#define SCHUNK 8192
#define NBLK2 ((NEDGES + SCHUNK - 1) / SCHUNK)               // 196

typedef __attribute__((ext_vector_type(8))) short short8;
typedef __attribute__((ext_vector_type(4))) float f32x4;

// ---------------- pass A: per-block bucket histogram -> cnt[blk][NBUCK] (no atomics) --
__global__ __launch_bounds__(1024) void hist2(const int* __restrict__ dst,
                                              int* __restrict__ cnt, int E) {
    __shared__ int h[NBUCK];
    for (int i = threadIdx.x; i < NBUCK; i += 1024) h[i] = 0;
    __syncthreads();
    int base = blockIdx.x * SCHUNK;
    #pragma unroll
    for (int j = 0; j < 8; j++) {
        int e = base + threadIdx.x + j * 1024;
        if (e < E) atomicAdd(&h[dst[e] >> BUCKET_SHIFT], 1);
    }
    __syncthreads();
    for (int i = threadIdx.x; i < NBUCK; i += 1024)
        cnt[blockIdx.x * NBUCK + i] = h[i];
}

// ---------------- per-bucket exclusive scan over blocks -> bstart[blk][b], btot[b] ----
__global__ void bscan1(const int* __restrict__ cnt, int* __restrict__ bstart,
                       int* __restrict__ btot) {
    int b = blockIdx.x;      // one 64-thread wave per bucket
    int l = threadIdx.x;
    int vals[4];
    int s = 0;
    #pragma unroll
    for (int i = 0; i < 4; i++) {
        int blk = l * 4 + i;
        vals[i] = (blk < NBLK2) ? cnt[blk * NBUCK + b] : 0;
        s += vals[i];
    }
    int pre = s;
    for (int off = 1; off < 64; off <<= 1) {
        int t = __shfl_up(pre, off, 64);
        if (l >= off) pre += t;
    }
    pre -= s;  // exclusive prefix of this lane's group
    int run = pre;
    #pragma unroll
    for (int i = 0; i < 4; i++) {
        int blk = l * 4 + i;
        if (blk < NBLK2) { bstart[blk * NBUCK + b] = run; run += vals[i]; }
    }
    if (l == 63) btot[b] = pre + s;
}

// ---------------- scan bucket totals -> segoff[0..NBUCK] ----------------
__global__ void segscan2(const int* __restrict__ btot, int* __restrict__ segoff) {
    __shared__ int lds[256];
    int t = threadIdx.x;
    int b0 = t * 4;
    int v[4];
    int s = 0;
    #pragma unroll
    for (int i = 0; i < 4; i++) { int b = b0 + i; v[i] = (b < NBUCK) ? btot[b] : 0; s += v[i]; }
    lds[t] = s;
    __syncthreads();
    for (int off = 1; off < 256; off <<= 1) {
        int x = lds[t];
        int a = (t >= off) ? lds[t - off] : 0;
        __syncthreads();
        lds[t] = x + a;
        __syncthreads();
    }
    int run = lds[t] - s;
    #pragma unroll
    for (int i = 0; i < 4; i++) {
        int b = b0 + i;
        if (b < NBUCK) { segoff[b] = run; run += v[i]; }
    }
    if (t == 255) segoff[NBUCK] = lds[255];
}

// ---------------- pass B: LDS counting-sort scatter, burst coalesced writes ----------
__global__ __launch_bounds__(1024) void scatter2(const int* __restrict__ src,
                                                 const int* __restrict__ dst,
                                                 const int* __restrict__ bstart,
                                                 const int* __restrict__ segoff,
                                                 unsigned int* __restrict__ stage, int E) {
    __shared__ unsigned int rec[SCHUNK];     // 32 KB sorted records
    __shared__ unsigned short bid[SCHUNK];   // 16 KB bucket id per slot
    __shared__ int hs[1024];                 // per-bucket counts
    __shared__ int wsum[16];
    __shared__ int cur[NBUCK];               // local cursors
    __shared__ int delta[NBUCK];             // global dest - local slot
    __shared__ int nrec_s;
    int tid = threadIdx.x, lane = tid & 63, wid = tid >> 6;
    int base = blockIdx.x * SCHUNK;
    hs[tid] = 0;
    __syncthreads();
    int myd[8], mys[8];
    #pragma unroll
    for (int j = 0; j < 8; j++) {
        int e = base + tid + j * 1024;
        if (e < E) {
            myd[j] = dst[e];
            mys[j] = src[e];
            atomicAdd(&hs[myd[j] >> BUCKET_SHIFT], 1);
        } else myd[j] = -1;
    }
    __syncthreads();
    int cnt_t = hs[tid];
    // wave-level inclusive scan (no barriers), then cross-wave via LDS
    int pre = cnt_t;
    for (int off = 1; off < 64; off <<= 1) {
        int t = __shfl_up(pre, off, 64);
        if (lane >= off) pre += t;
    }
    if (lane == 63) wsum[wid] = pre;
    __syncthreads();
    if (tid == 0) {
        int r = 0;
        #pragma unroll
        for (int i = 0; i < 16; i++) { int t = wsum[i]; wsum[i] = r; r += t; }
        nrec_s = r;
    }
    __syncthreads();
    int excl = pre - cnt_t + wsum[wid];
    if (tid < NBUCK) {
        cur[tid] = excl;
        delta[tid] = segoff[tid] + bstart[blockIdx.x * NBUCK + tid] - excl;
    }
    __syncthreads();
    #pragma unroll
    for (int j = 0; j < 8; j++) {
        if (myd[j] >= 0) {
            int b = myd[j] >> BUCKET_SHIFT;
            int p = atomicAdd(&cur[b], 1);
            rec[p] = (unsigned int)mys[j] | (((unsigned int)myd[j] & 127u) << 17);
            bid[p] = (unsigned short)b;
        }
    }
    __syncthreads();
    int nrec = nrec_s;
    for (int i = tid; i < nrec; i += 1024)
        stage[delta[bid[i]] + i] = rec[i];
}

// ---------------- pass C1: per-bucket LDS histogram -> deg (streaming writes) --------
__global__ void bucket_deg(const unsigned int* __restrict__ stage, const int* __restrict__ segoff,
                           int* __restrict__ deg, int n) {
    __shared__ int h[BUCKET_NODES];
    int b = blockIdx.x;
    if (threadIdx.x < BUCKET_NODES) h[threadIdx.x] = 0;
    __syncthreads();
    int s0 = segoff[b], s1 = segoff[b + 1];
    for (int i = s0 + threadIdx.x; i < s1; i += 256)
        atomicAdd(&h[(stage[i] >> 17) & 127u], 1);
    __syncthreads();
    int v = b * BUCKET_NODES + threadIdx.x;
    if (threadIdx.x < BUCKET_NODES && v < n) deg[v] = h[threadIdx.x];
}

// ---------------- hierarchical scan of (deg[v]+1); also emits dinv ----------------
__global__ void scan1_kernel(const int* __restrict__ deg, int* __restrict__ psum,
                             float* __restrict__ dinv, int n) {
    __shared__ int lds[256];
    int t = threadIdx.x;
    int base = blockIdx.x * SCAN_CHUNK + t * 8;
    int s = 0;
    #pragma unroll
    for (int i = 0; i < 8; i++) {
        int idx = base + i;
        if (idx < n) {
            int d = deg[idx];
            dinv[idx] = rsqrtf((float)d + 1.0f);
            s += d + 1;
        }
    }
    lds[t] = s;
    __syncthreads();
    for (int off = 128; off > 0; off >>= 1) {
        if (t < off) lds[t] += lds[t + off];
        __syncthreads();
    }
    if (t == 0) psum[blockIdx.x] = lds[0];
}

__global__ void scan2_kernel(int* __restrict__ psum, int* __restrict__ offs, int nb, int n) {
    __shared__ int lds[64];
    int t = threadIdx.x;  // 64 threads
    int v = (t < nb) ? psum[t] : 0;
    lds[t] = v;
    __syncthreads();
    for (int off = 1; off < 64; off <<= 1) {
        int x = lds[t];
        int add = (t >= off) ? lds[t - off] : 0;
        __syncthreads();
        lds[t] = x + add;
        __syncthreads();
    }
    if (t < nb) psum[t] = lds[t] - v;  // exclusive prefix of block sums
    if (t == 63) offs[n] = lds[63];    // grand total
}

// scan3: offs[] only
__global__ void scan3_kernel(const int* __restrict__ deg, const int* __restrict__ psum,
                             int* __restrict__ offs, int n) {
    __shared__ int lds[256];
    int t = threadIdx.x;
    int base = blockIdx.x * SCAN_CHUNK + t * 8;
    int dv[8];
    int s = 0;
    #pragma unroll
    for (int i = 0; i < 8; i++) {
        int idx = base + i;
        dv[i] = (idx < n) ? deg[idx] + 1 : 0;
        s += dv[i];
    }
    lds[t] = s;
    __syncthreads();
    for (int off = 1; off < 256; off <<= 1) {
        int x = lds[t];
        int add = (t >= off) ? lds[t - off] : 0;
        __syncthreads();
        lds[t] = x + add;
        __syncthreads();
    }
    int run = psum[blockIdx.x] + lds[t] - s;
    #pragma unroll
    for (int i = 0; i < 8; i++) {
        int idx = base + i;
        if (idx < n) { offs[idx] = run; run += dv[i]; }
    }
}

// ---------------- pass C2: place csrc (self + edges) within bucket's contiguous region
__global__ void bucket_place(const unsigned int* __restrict__ stage, const int* __restrict__ segoff,
                             const int* __restrict__ offs, int* __restrict__ csrc, int n) {
    __shared__ int cur[BUCKET_NODES];
    int b = blockIdx.x;
    int v = b * BUCKET_NODES + threadIdx.x;
    if (threadIdx.x < BUCKET_NODES && v < n) {
        int o = offs[v];
        csrc[o] = v;                 // slot 0 = self loop
        cur[threadIdx.x] = o + 1;
    }
    __syncthreads();
    int s0 = segoff[b], s1 = segoff[b + 1];
    for (int i = s0 + threadIdx.x; i < s1; i += 256) {
        unsigned int r = stage[i];
        int pos = atomicAdd(&cur[(r >> 17) & 127u], 1);
        csrc[pos] = (int)(r & 0x1ffffu);
    }
}

// RNE pack: two f32 -> bf16x2 (lo = a, hi = b)
__device__ __forceinline__ unsigned int pack_bf16x2(float a, float b) {
    unsigned int ua = __float_as_uint(a);
    unsigned int ub = __float_as_uint(b);
    ua += 0x7fffu + ((ua >> 16) & 1u);
    ub += 0x7fffu + ((ub >> 16) & 1u);
    return (ua >> 16) | (ub & 0xffff0000u);
}

// split f32 -> (hi bf16, lo bf16): w ~= hi + lo, error ~2^-17 relative
__device__ __forceinline__ void split_bf16(float w, unsigned short& h, unsigned short& l) {
    unsigned int uw = __float_as_uint(w);
    unsigned int hb = uw + 0x7fffu + ((uw >> 16) & 1u);
    h = (unsigned short)(hb >> 16);
    float rem = w - __uint_as_float((unsigned int)h << 16);
    unsigned int ur = __float_as_uint(rem);
    unsigned int lb = ur + 0x7fffu + ((ur >> 16) & 1u);
    l = (unsigned short)(lb >> 16);
}

// ---------------- W prep (both weights in one launch): frag-major split-bf16 ----------
__global__ void wprep2(const float* __restrict__ W1, const float* __restrict__ W2,
                       unsigned short* __restrict__ Wh1, unsigned short* __restrict__ Wl1,
                       unsigned short* __restrict__ Wh2, unsigned short* __restrict__ Wl2) {
    int gidx = blockIdx.x * 256 + threadIdx.x;  // 0..4095
    int which = gidx >> 11;
    int id = gidx & 2047;
    const float* W = which ? W2 : W1;
    unsigned short* Wh = which ? Wh2 : Wh1;
    unsigned short* Wl = which ? Wl2 : Wl1;
    int lane = id & 63, tq = id >> 6;
    int t = tq >> 2, q = tq & 3;
    int n = 16 * t + (lane & 15);
    int kbase = 32 * q + 8 * (lane >> 4);
    unsigned short h[8], l[8];
    #pragma unroll
    for (int i = 0; i < 8; i++) {
        split_bf16(W[(kbase + i) * DF + n], h[i], l[i]);
    }
    uint4 hv, lv;
    hv.x = h[0] | ((unsigned int)h[1] << 16); hv.y = h[2] | ((unsigned int)h[3] << 16);
    hv.z = h[4] | ((unsigned int)h[5] << 16); hv.w = h[6] | ((unsigned int)h[7] << 16);
    lv.x = l[0] | ((unsigned int)l[1] << 16); lv.y = l[2] | ((unsigned int)l[3] << 16);
    lv.z = l[4] | ((unsigned int)l[5] << 16); lv.w = l[6] | ((unsigned int)l[7] << 16);
    ((uint4*)Wh)[id] = hv;
    ((uint4*)Wl)[id] = lv;
}

// ---------------- MFMA GEMM: C_bf16[n,128] = dinv[n] * (A[n,128] @ W[128,128]) --------
template <int ABF16>
__global__ void gemm_mfma(const void* __restrict__ Ap, const unsigned short* __restrict__ Wh,
                          const unsigned short* __restrict__ Wl, const float* __restrict__ dinv,
                          unsigned int* __restrict__ C, int nrows) {
    int tid = threadIdx.x;
    int wv = tid >> 6, lane = tid & 63;
    int c16 = lane & 15, g = lane >> 4;
    int row = blockIdx.x * 64 + wv * 16 + c16;
    int rowc = min(row, nrows - 1);
    const short8* Wh8 = (const short8*)Wh;
    const short8* Wl8 = (const short8*)Wl;
    f32x4 acc[8];
    #pragma unroll
    for (int t = 0; t < 8; t++) acc[t] = (f32x4){0.f, 0.f, 0.f, 0.f};
    #pragma unroll
    for (int q = 0; q < 4; q++) {
        short8 ah, al;
        if (ABF16) {
            ah = ((const short8*)Ap)[(size_t)rowc * 16 + q * 4 + g];
        } else {
            const float4* A4 = (const float4*)Ap;
            float4 a0 = A4[(size_t)rowc * 32 + q * 8 + g * 2];
            float4 a1 = A4[(size_t)rowc * 32 + q * 8 + g * 2 + 1];
            float av[8] = {a0.x, a0.y, a0.z, a0.w, a1.x, a1.y, a1.z, a1.w};
            #pragma unroll
            for (int i = 0; i < 8; i++) {
                unsigned short hs, ls;
                split_bf16(av[i], hs, ls);
                ah[i] = (short)hs;
                al[i] = (short)ls;
            }
        }
        #pragma unroll
        for (int t = 0; t < 8; t++) {
            short8 wh = Wh8[(t * 4 + q) * 64 + lane];
            short8 wl = Wl8[(t * 4 + q) * 64 + lane];
            acc[t] = __builtin_amdgcn_mfma_f32_16x16x32_bf16(wh, ah, acc[t], 0, 0, 0);
            if (!ABF16) acc[t] = __builtin_amdgcn_mfma_f32_16x16x32_bf16(wh, al, acc[t], 0, 0, 0);
            acc[t] = __builtin_amdgcn_mfma_f32_16x16x32_bf16(wl, ah, acc[t], 0, 0, 0);
        }
    }
    if (row < nrows) {
        float dvr = dinv[row];
        uint2* C2 = (uint2*)C;
        #pragma unroll
        for (int t = 0; t < 8; t++) {
            uint2 w;
            w.x = pack_bf16x2(acc[t][0] * dvr, acc[t][1] * dvr);
            w.y = pack_bf16x2(acc[t][2] * dvr, acc[t][3] * dvr);
            C2[(size_t)row * 32 + t * 4 + g] = w;
        }
    }
}

// ---------------- CSR aggregation (R12 structure, unroll 16): out[v] = epi(dinv[v]*sum)
// 4B/lane, one 256B row per gather instruction, 16 independent gathers in flight.
template <int BIAS_RELU, int OUT16>
__global__ void agg_kernel(const int* __restrict__ roff, const int* __restrict__ csrc,
                           const float* __restrict__ dinv, const unsigned int* __restrict__ Hb,
                           const float* __restrict__ bias, void* __restrict__ Out) {
    int tid = threadIdx.x;
    int wv = tid >> 6, lane = tid & 63;
    size_t v = (size_t)blockIdx.x * 4 + wv;
    int b = roff[v], e = roff[v + 1];
    float2 acc = {0.f, 0.f};
    for (int base = b; base < e; base += 64) {
        int idx = base + lane;
        if (idx >= e) idx = e - 1;       // clamped dup, never consumed
        int rec = csrc[idx];             // one coalesced 256B record load
        int kmax = min(64, e - base);
        int k = 0;
        for (; k + 16 <= kmax; k += 16) {
            unsigned int u[16];
            #pragma unroll
            for (int j = 0; j < 16; j++) {
                int s = __shfl(rec, k + j, 64);
                u[j] = Hb[(size_t)s * 64 + lane];      // 256B row gather
            }
            #pragma unroll
            for (int j = 0; j < 16; j++) {
                acc.x += __uint_as_float(u[j] << 16);
                acc.y += __uint_as_float(u[j] & 0xffff0000u);
            }
        }
        for (; k + 8 <= kmax; k += 8) {
            unsigned int u[8];
            #pragma unroll
            for (int j = 0; j < 8; j++) {
                int s = __shfl(rec, k + j, 64);
                u[j] = Hb[(size_t)s * 64 + lane];
            }
            #pragma unroll
            for (int j = 0; j < 8; j++) {
                acc.x += __uint_as_float(u[j] << 16);
                acc.y += __uint_as_float(u[j] & 0xffff0000u);
            }
        }
        for (; k < kmax; k++) {
            int s0 = __shfl(rec, k, 64);
            unsigned int u0 = Hb[(size_t)s0 * 64 + lane];
            acc.x += __uint_as_float(u0 << 16);
            acc.y += __uint_as_float(u0 & 0xffff0000u);
        }
    }
    float dvv = dinv[v];
    acc.x *= dvv;
    acc.y *= dvv;
    if (BIAS_RELU) {
        float2 bb = ((const float2*)bias)[lane];
        acc.x = fmaxf(acc.x + bb.x, 0.f);
        acc.y = fmaxf(acc.y + bb.y, 0.f);
    }
    if (OUT16) {
        ((unsigned int*)Out)[v * 64 + lane] = pack_bf16x2(acc.x, acc.y);
    } else {
        ((float2*)Out)[v * 64 + lane] = acc;
    }
}

// ---------------- segmented mean-pool (batch sorted) ----------------
__global__ void pool_kernel(const float* __restrict__ H, const int* __restrict__ batch,
                            float* __restrict__ gsum, float* __restrict__ gcnt, int n) {
    __shared__ int bl[128];
    int d = threadIdx.x;
    int base = blockIdx.x * 128;
    int cnt_here = min(128, n - base);
    if (cnt_here <= 0) return;
    if (d < cnt_here) bl[d] = batch[base + d];
    __syncthreads();
    float acc = 0.f;
    int cg = -1, c = 0;
    for (int i = 0; i < cnt_here; i++) {
        int g = bl[i];
        if (g != cg) {
            if (cg >= 0) {
                atomicAdd(&gsum[cg * DF + d], acc);
                if (d == 0) atomicAdd(&gcnt[cg], (float)c);
            }
            acc = 0.f; c = 0; cg = g;
        }
        acc += H[(size_t)(base + i) * DF + d];
        c++;
    }
    if (cg >= 0) {
        atomicAdd(&gsum[cg * DF + d], acc);
        if (d == 0) atomicAdd(&gcnt[cg], (float)c);
    }
}

// ---------------- final: out[g] = dot(gsum[g]/cnt + b2, Wm) + bm ----------------
__global__ void final_kernel(const float* __restrict__ gsum, const float* __restrict__ gcnt,
                             const float* __restrict__ b2, const float* __restrict__ Wm,
                             const float* __restrict__ bm, float* __restrict__ out) {
    __shared__ float red[2];
    int g = blockIdx.x, d = threadIdx.x;
    float cnt = fmaxf(gcnt[g], 1.0f);
    float v = (gsum[g * DF + d] / cnt + b2[d]) * Wm[d];
    for (int off = 32; off > 0; off >>= 1) v += __shfl_down(v, off, 64);
    if ((d & 63) == 0) red[d >> 6] = v;
    __syncthreads();
    if (d == 0) out[g] = red[0] + red[1] + bm[0];
}

extern "C" void kernel_launch(void* const* d_in, const int* in_sizes, int n_in,
                              void* d_out, int out_size, void* d_ws, size_t ws_size,
                              hipStream_t stream) {
    const float* x   = (const float*)d_in[0];
    const int*   ei  = (const int*)d_in[1];   // [2, E] flat: first E = src, next E = dst
    const int*   bat = (const int*)d_in[2];
    const float* W1  = (const float*)d_in[3];
    const float* b1  = (const float*)d_in[4];
    const float* W2  = (const float*)d_in[5];
    const float* b2  = (const float*)d_in[6];
    const float* Wm  = (const float*)d_in[7];
    const float* bm  = (const float*)d_in[8];
    float* out = (float*)d_out;

    const int N = NNODES, E = NEDGES, G = NGRAPH;
    const int* src = ei;
    const int* dst = ei + E;

    // workspace carve
    char* base = (char*)d_ws;
    size_t o = 0;
    auto alloc = [&](size_t bytes) { size_t p = o; o = (o + bytes + 255) & ~(size_t)255; return p; };
    int*   deg    = (int*)(base + alloc((size_t)N * 4));
    int*   offs   = (int*)(base + alloc((size_t)(N + 1) * 4));
    float* dinv   = (float*)(base + alloc((size_t)N * 4));
    int*   psum   = (int*)(base + alloc((size_t)NB_SCAN * 4));
    int*   cnt    = (int*)(base + alloc((size_t)NBLK2 * NBUCK * 4));
    int*   bstart = (int*)(base + alloc((size_t)NBLK2 * NBUCK * 4));
    int*   btot   = (int*)(base + alloc((size_t)NBUCK * 4));
    int*   segoff = (int*)(base + alloc((size_t)(NBUCK + 1) * 4));
    unsigned int* stage = (unsigned int*)(base + alloc((size_t)E * 4));
    int*   csrc   = (int*)(base + alloc((size_t)(E + N) * 4));
    unsigned int* bufH  = (unsigned int*)(base + alloc((size_t)N * DF * 2));  // bf16 H (dinv-scaled)
    unsigned int* bufA16 = (unsigned int*)(base + alloc((size_t)N * DF * 2)); // bf16 layer-1 output
    float* bufB   = (float*)(base + alloc((size_t)N * DF * 4));
    float* gsum   = (float*)(base + alloc((size_t)G * DF * 4));
    float* gcnt   = (float*)(base + alloc((size_t)G * 4));
    unsigned short* wh1 = (unsigned short*)(base + alloc(2048 * 16));
    unsigned short* wl1 = (unsigned short*)(base + alloc(2048 * 16));
    unsigned short* wh2 = (unsigned short*)(base + alloc(2048 * 16));
    unsigned short* wl2 = (unsigned short*)(base + alloc(2048 * 16));
    (void)ws_size;

    hipMemsetAsync(gsum, 0, (size_t)G * DF * 4, stream);
    hipMemsetAsync(gcnt, 0, (size_t)G * 4, stream);

    // atomic-free binned CSR build
    hist2<<<NBLK2, 1024, 0, stream>>>(dst, cnt, E);
    bscan1<<<NBUCK, 64, 0, stream>>>(cnt, bstart, btot);
    segscan2<<<1, 256, 0, stream>>>(btot, segoff);
    scatter2<<<NBLK2, 1024, 0, stream>>>(src, dst, bstart, segoff, stage, E);
    bucket_deg<<<NBUCK, 256, 0, stream>>>(stage, segoff, deg, N);
    scan1_kernel<<<NB_SCAN, 256, 0, stream>>>(deg, psum, dinv, N);
    scan2_kernel<<<1, 64, 0, stream>>>(psum, offs, NB_SCAN, N);
    scan3_kernel<<<NB_SCAN, 256, 0, stream>>>(deg, psum, offs, N);
    bucket_place<<<NBUCK, 256, 0, stream>>>(stage, segoff, offs, csrc, N);

    // W prep (both layers, one launch)
    wprep2<<<16, 256, 0, stream>>>(W1, W2, wh1, wl1, wh2, wl2);

    // layer 1: bufH = bf16(dinv .* (x @ W1)) ; bufA16 = bf16(relu(dinv[v]*sum + b1))
    gemm_mfma<0><<<(N + 63) / 64, 256, 0, stream>>>(x, wh1, wl1, dinv, bufH, N);
    agg_kernel<1, 1><<<N / 4, 256, 0, stream>>>(offs, csrc, dinv, bufH, b1, bufA16);

    // layer 2: bufH = bf16(dinv .* (bufA16 @ W2)) ; bufB = dinv[v]*sum (fp32)
    gemm_mfma<1><<<(N + 63) / 64, 256, 0, stream>>>(bufA16, wh2, wl2, dinv, bufH, N);
    agg_kernel<0, 0><<<N / 4, 256, 0, stream>>>(offs, csrc, dinv, bufH, nullptr, bufB);

    // pool + final
    pool_kernel<<<(N + 127) / 128, 128, 0, stream>>>(bufB, bat, gsum, gcnt, N);
    final_kernel<<<G, 128, 0, stream>>>(gsum, gcnt, b2, Wm, bm, out);
}

// Round 16
// 275.861 us; speedup vs baseline: 1.1481x; 1.0169x over previous
//
#include <hip/hip_runtime.h>
#include <hip/hip_bf16.h>

#define NNODES 100000
#define NEDGES 1600000
#define DF 128
#define NGRAPH 256
#define SCAN_CHUNK 2048
#define NB_SCAN ((NNODES + SCAN_CHUNK - 1) / SCAN_CHUNK)

#define BUCKET_SHIFT 7
#define BUCKET_NODES 128
#define NBUCK ((NNODES + BUCKET_NODES - 1) / BUCKET_NODES)   // 782
#define SCHUNK 8192
#define NBLK2 ((NEDGES + SCHUNK - 1) / SCHUNK)               // 196

typedef __attribute__((ext_vector_type(8))) short short8;
typedef __attribute__((ext_vector_type(4))) float f32x4;

// ---------------- pass A: per-block bucket histogram -> cnt[blk][NBUCK] (no atomics) --
__global__ __launch_bounds__(1024) void hist2(const int* __restrict__ dst,
                                              int* __restrict__ cnt, int E) {
    __shared__ int h[NBUCK];
    for (int i = threadIdx.x; i < NBUCK; i += 1024) h[i] = 0;
    __syncthreads();
    int base = blockIdx.x * SCHUNK;
    #pragma unroll
    for (int j = 0; j < 8; j++) {
        int e = base + threadIdx.x + j * 1024;
        if (e < E) atomicAdd(&h[dst[e] >> BUCKET_SHIFT], 1);
    }
    __syncthreads();
    for (int i = threadIdx.x; i < NBUCK; i += 1024)
        cnt[blockIdx.x * NBUCK + i] = h[i];
}

// ---------------- per-bucket exclusive scan over blocks -> bstart[blk][b], btot[b] ----
__global__ void bscan1(const int* __restrict__ cnt, int* __restrict__ bstart,
                       int* __restrict__ btot) {
    int b = blockIdx.x;      // one 64-thread wave per bucket
    int l = threadIdx.x;
    int vals[4];
    int s = 0;
    #pragma unroll
    for (int i = 0; i < 4; i++) {
        int blk = l * 4 + i;
        vals[i] = (blk < NBLK2) ? cnt[blk * NBUCK + b] : 0;
        s += vals[i];
    }
    int pre = s;
    for (int off = 1; off < 64; off <<= 1) {
        int t = __shfl_up(pre, off, 64);
        if (l >= off) pre += t;
    }
    pre -= s;  // exclusive prefix of this lane's group
    int run = pre;
    #pragma unroll
    for (int i = 0; i < 4; i++) {
        int blk = l * 4 + i;
        if (blk < NBLK2) { bstart[blk * NBUCK + b] = run; run += vals[i]; }
    }
    if (l == 63) btot[b] = pre + s;
}

// ---------------- scan bucket totals -> segoff[0..NBUCK] ----------------
__global__ void segscan2(const int* __restrict__ btot, int* __restrict__ segoff) {
    __shared__ int lds[256];
    int t = threadIdx.x;
    int b0 = t * 4;
    int v[4];
    int s = 0;
    #pragma unroll
    for (int i = 0; i < 4; i++) { int b = b0 + i; v[i] = (b < NBUCK) ? btot[b] : 0; s += v[i]; }
    lds[t] = s;
    __syncthreads();
    for (int off = 1; off < 256; off <<= 1) {
        int x = lds[t];
        int a = (t >= off) ? lds[t - off] : 0;
        __syncthreads();
        lds[t] = x + a;
        __syncthreads();
    }
    int run = lds[t] - s;
    #pragma unroll
    for (int i = 0; i < 4; i++) {
        int b = b0 + i;
        if (b < NBUCK) { segoff[b] = run; run += v[i]; }
    }
    if (t == 255) segoff[NBUCK] = lds[255];
}

// ---------------- pass B: LDS counting-sort scatter, burst coalesced writes ----------
__global__ __launch_bounds__(1024) void scatter2(const int* __restrict__ src,
                                                 const int* __restrict__ dst,
                                                 const int* __restrict__ bstart,
                                                 const int* __restrict__ segoff,
                                                 unsigned int* __restrict__ stage, int E) {
    __shared__ unsigned int rec[SCHUNK];     // 32 KB sorted records
    __shared__ unsigned short bid[SCHUNK];   // 16 KB bucket id per slot
    __shared__ int hs[1024];                 // per-bucket counts
    __shared__ int wsum[16];
    __shared__ int cur[NBUCK];               // local cursors
    __shared__ int delta[NBUCK];             // global dest - local slot
    __shared__ int nrec_s;
    int tid = threadIdx.x, lane = tid & 63, wid = tid >> 6;
    int base = blockIdx.x * SCHUNK;
    hs[tid] = 0;
    __syncthreads();
    int myd[8], mys[8];
    #pragma unroll
    for (int j = 0; j < 8; j++) {
        int e = base + tid + j * 1024;
        if (e < E) {
            myd[j] = dst[e];
            mys[j] = src[e];
            atomicAdd(&hs[myd[j] >> BUCKET_SHIFT], 1);
        } else myd[j] = -1;
    }
    __syncthreads();
    int cnt_t = hs[tid];
    // wave-level inclusive scan (no barriers), then cross-wave via LDS
    int pre = cnt_t;
    for (int off = 1; off < 64; off <<= 1) {
        int t = __shfl_up(pre, off, 64);
        if (lane >= off) pre += t;
    }
    if (lane == 63) wsum[wid] = pre;
    __syncthreads();
    if (tid == 0) {
        int r = 0;
        #pragma unroll
        for (int i = 0; i < 16; i++) { int t = wsum[i]; wsum[i] = r; r += t; }
        nrec_s = r;
    }
    __syncthreads();
    int excl = pre - cnt_t + wsum[wid];
    if (tid < NBUCK) {
        cur[tid] = excl;
        delta[tid] = segoff[tid] + bstart[blockIdx.x * NBUCK + tid] - excl;
    }
    __syncthreads();
    #pragma unroll
    for (int j = 0; j < 8; j++) {
        if (myd[j] >= 0) {
            int b = myd[j] >> BUCKET_SHIFT;
            int p = atomicAdd(&cur[b], 1);
            rec[p] = (unsigned int)mys[j] | (((unsigned int)myd[j] & 127u) << 17);
            bid[p] = (unsigned short)b;
        }
    }
    __syncthreads();
    int nrec = nrec_s;
    for (int i = tid; i < nrec; i += 1024)
        stage[delta[bid[i]] + i] = rec[i];
}

// ---------------- pass C1: per-bucket LDS histogram -> deg (streaming writes) --------
__global__ void bucket_deg(const unsigned int* __restrict__ stage, const int* __restrict__ segoff,
                           int* __restrict__ deg, int n) {
    __shared__ int h[BUCKET_NODES];
    int b = blockIdx.x;
    if (threadIdx.x < BUCKET_NODES) h[threadIdx.x] = 0;
    __syncthreads();
    int s0 = segoff[b], s1 = segoff[b + 1];
    for (int i = s0 + threadIdx.x; i < s1; i += 256)
        atomicAdd(&h[(stage[i] >> 17) & 127u], 1);
    __syncthreads();
    int v = b * BUCKET_NODES + threadIdx.x;
    if (threadIdx.x < BUCKET_NODES && v < n) deg[v] = h[threadIdx.x];
}

// ---------------- hierarchical scan of (deg[v]+1); also emits dinv ----------------
__global__ void scan1_kernel(const int* __restrict__ deg, int* __restrict__ psum,
                             float* __restrict__ dinv, int n) {
    __shared__ int lds[256];
    int t = threadIdx.x;
    int base = blockIdx.x * SCAN_CHUNK + t * 8;
    int s = 0;
    #pragma unroll
    for (int i = 0; i < 8; i++) {
        int idx = base + i;
        if (idx < n) {
            int d = deg[idx];
            dinv[idx] = rsqrtf((float)d + 1.0f);
            s += d + 1;
        }
    }
    lds[t] = s;
    __syncthreads();
    for (int off = 128; off > 0; off >>= 1) {
        if (t < off) lds[t] += lds[t + off];
        __syncthreads();
    }
    if (t == 0) psum[blockIdx.x] = lds[0];
}

__global__ void scan2_kernel(int* __restrict__ psum, int* __restrict__ offs, int nb, int n) {
    __shared__ int lds[64];
    int t = threadIdx.x;  // 64 threads
    int v = (t < nb) ? psum[t] : 0;
    lds[t] = v;
    __syncthreads();
    for (int off = 1; off < 64; off <<= 1) {
        int x = lds[t];
        int add = (t >= off) ? lds[t - off] : 0;
        __syncthreads();
        lds[t] = x + add;
        __syncthreads();
    }
    if (t < nb) psum[t] = lds[t] - v;  // exclusive prefix of block sums
    if (t == 63) offs[n] = lds[63];    // grand total
}

// scan3: offs[] only
__global__ void scan3_kernel(const int* __restrict__ deg, const int* __restrict__ psum,
                             int* __restrict__ offs, int n) {
    __shared__ int lds[256];
    int t = threadIdx.x;
    int base = blockIdx.x * SCAN_CHUNK + t * 8;
    int dv[8];
    int s = 0;
    #pragma unroll
    for (int i = 0; i < 8; i++) {
        int idx = base + i;
        dv[i] = (idx < n) ? deg[idx] + 1 : 0;
        s += dv[i];
    }
    lds[t] = s;
    __syncthreads();
    for (int off = 1; off < 256; off <<= 1) {
        int x = lds[t];
        int add = (t >= off) ? lds[t - off] : 0;
        __syncthreads();
        lds[t] = x + add;
        __syncthreads();
    }
    int run = psum[blockIdx.x] + lds[t] - s;
    #pragma unroll
    for (int i = 0; i < 8; i++) {
        int idx = base + i;
        if (idx < n) { offs[idx] = run; run += dv[i]; }
    }
}

// ---------------- pass C2: place csrc (self + edges) within bucket's contiguous region
__global__ void bucket_place(const unsigned int* __restrict__ stage, const int* __restrict__ segoff,
                             const int* __restrict__ offs, int* __restrict__ csrc, int n) {
    __shared__ int cur[BUCKET_NODES];
    int b = blockIdx.x;
    int v = b * BUCKET_NODES + threadIdx.x;
    if (threadIdx.x < BUCKET_NODES && v < n) {
        int o = offs[v];
        csrc[o] = v;                 // slot 0 = self loop
        cur[threadIdx.x] = o + 1;
    }
    __syncthreads();
    int s0 = segoff[b], s1 = segoff[b + 1];
    for (int i = s0 + threadIdx.x; i < s1; i += 256) {
        unsigned int r = stage[i];
        int pos = atomicAdd(&cur[(r >> 17) & 127u], 1);
        csrc[pos] = (int)(r & 0x1ffffu);
    }
}

// RNE pack: two f32 -> bf16x2 (lo = a, hi = b)
__device__ __forceinline__ unsigned int pack_bf16x2(float a, float b) {
    unsigned int ua = __float_as_uint(a);
    unsigned int ub = __float_as_uint(b);
    ua += 0x7fffu + ((ua >> 16) & 1u);
    ub += 0x7fffu + ((ub >> 16) & 1u);
    return (ua >> 16) | (ub & 0xffff0000u);
}

// split f32 -> (hi bf16, lo bf16): w ~= hi + lo, error ~2^-17 relative
__device__ __forceinline__ void split_bf16(float w, unsigned short& h, unsigned short& l) {
    unsigned int uw = __float_as_uint(w);
    unsigned int hb = uw + 0x7fffu + ((uw >> 16) & 1u);
    h = (unsigned short)(hb >> 16);
    float rem = w - __uint_as_float((unsigned int)h << 16);
    unsigned int ur = __float_as_uint(rem);
    unsigned int lb = ur + 0x7fffu + ((ur >> 16) & 1u);
    l = (unsigned short)(lb >> 16);
}

// ---------------- W prep (both weights in one launch): frag-major split-bf16 ----------
__global__ void wprep2(const float* __restrict__ W1, const float* __restrict__ W2,
                       unsigned short* __restrict__ Wh1, unsigned short* __restrict__ Wl1,
                       unsigned short* __restrict__ Wh2, unsigned short* __restrict__ Wl2) {
    int gidx = blockIdx.x * 256 + threadIdx.x;  // 0..4095
    int which = gidx >> 11;
    int id = gidx & 2047;
    const float* W = which ? W2 : W1;
    unsigned short* Wh = which ? Wh2 : Wh1;
    unsigned short* Wl = which ? Wl2 : Wl1;
    int lane = id & 63, tq = id >> 6;
    int t = tq >> 2, q = tq & 3;
    int n = 16 * t + (lane & 15);
    int kbase = 32 * q + 8 * (lane >> 4);
    unsigned short h[8], l[8];
    #pragma unroll
    for (int i = 0; i < 8; i++) {
        split_bf16(W[(kbase + i) * DF + n], h[i], l[i]);
    }
    uint4 hv, lv;
    hv.x = h[0] | ((unsigned int)h[1] << 16); hv.y = h[2] | ((unsigned int)h[3] << 16);
    hv.z = h[4] | ((unsigned int)h[5] << 16); hv.w = h[6] | ((unsigned int)h[7] << 16);
    lv.x = l[0] | ((unsigned int)l[1] << 16); lv.y = l[2] | ((unsigned int)l[3] << 16);
    lv.z = l[4] | ((unsigned int)l[5] << 16); lv.w = l[6] | ((unsigned int)l[7] << 16);
    ((uint4*)Wh)[id] = hv;
    ((uint4*)Wl)[id] = lv;
}

// ---------------- MFMA GEMM: C_bf16[n,128] = dinv[n] * (A[n,128] @ W[128,128]) --------
template <int ABF16>
__global__ void gemm_mfma(const void* __restrict__ Ap, const unsigned short* __restrict__ Wh,
                          const unsigned short* __restrict__ Wl, const float* __restrict__ dinv,
                          unsigned int* __restrict__ C, int nrows) {
    int tid = threadIdx.x;
    int wv = tid >> 6, lane = tid & 63;
    int c16 = lane & 15, g = lane >> 4;
    int row = blockIdx.x * 64 + wv * 16 + c16;
    int rowc = min(row, nrows - 1);
    const short8* Wh8 = (const short8*)Wh;
    const short8* Wl8 = (const short8*)Wl;
    f32x4 acc[8];
    #pragma unroll
    for (int t = 0; t < 8; t++) acc[t] = (f32x4){0.f, 0.f, 0.f, 0.f};
    #pragma unroll
    for (int q = 0; q < 4; q++) {
        short8 ah, al;
        if (ABF16) {
            ah = ((const short8*)Ap)[(size_t)rowc * 16 + q * 4 + g];
        } else {
            const float4* A4 = (const float4*)Ap;
            float4 a0 = A4[(size_t)rowc * 32 + q * 8 + g * 2];
            float4 a1 = A4[(size_t)rowc * 32 + q * 8 + g * 2 + 1];
            float av[8] = {a0.x, a0.y, a0.z, a0.w, a1.x, a1.y, a1.z, a1.w};
            #pragma unroll
            for (int i = 0; i < 8; i++) {
                unsigned short hs, ls;
                split_bf16(av[i], hs, ls);
                ah[i] = (short)hs;
                al[i] = (short)ls;
            }
        }
        #pragma unroll
        for (int t = 0; t < 8; t++) {
            short8 wh = Wh8[(t * 4 + q) * 64 + lane];
            short8 wl = Wl8[(t * 4 + q) * 64 + lane];
            acc[t] = __builtin_amdgcn_mfma_f32_16x16x32_bf16(wh, ah, acc[t], 0, 0, 0);
            if (!ABF16) acc[t] = __builtin_amdgcn_mfma_f32_16x16x32_bf16(wh, al, acc[t], 0, 0, 0);
            acc[t] = __builtin_amdgcn_mfma_f32_16x16x32_bf16(wl, ah, acc[t], 0, 0, 0);
        }
    }
    if (row < nrows) {
        float dvr = dinv[row];
        uint2* C2 = (uint2*)C;
        #pragma unroll
        for (int t = 0; t < 8; t++) {
            uint2 w;
            w.x = pack_bf16x2(acc[t][0] * dvr, acc[t][1] * dvr);
            w.y = pack_bf16x2(acc[t][2] * dvr, acc[t][3] * dvr);
            C2[(size_t)row * 32 + t * 4 + g] = w;
        }
    }
}

// ---------------- CSR aggregation (R12 structure, unroll 16): out[v] = epi(dinv[v]*sum)
// 4B/lane, one 256B row per gather instruction, 16 independent gathers in flight.
// Output is always bf16 (one uint per lane).
template <int BIAS_RELU>
__global__ void agg_kernel(const int* __restrict__ roff, const int* __restrict__ csrc,
                           const float* __restrict__ dinv, const unsigned int* __restrict__ Hb,
                           const float* __restrict__ bias, unsigned int* __restrict__ Out) {
    int tid = threadIdx.x;
    int wv = tid >> 6, lane = tid & 63;
    size_t v = (size_t)blockIdx.x * 4 + wv;
    int b = roff[v], e = roff[v + 1];
    float2 acc = {0.f, 0.f};
    for (int base = b; base < e; base += 64) {
        int idx = base + lane;
        if (idx >= e) idx = e - 1;       // clamped dup, never consumed
        int rec = csrc[idx];             // one coalesced 256B record load
        int kmax = min(64, e - base);
        int k = 0;
        for (; k + 16 <= kmax; k += 16) {
            unsigned int u[16];
            #pragma unroll
            for (int j = 0; j < 16; j++) {
                int s = __shfl(rec, k + j, 64);
                u[j] = Hb[(size_t)s * 64 + lane];      // 256B row gather
            }
            #pragma unroll
            for (int j = 0; j < 16; j++) {
                acc.x += __uint_as_float(u[j] << 16);
                acc.y += __uint_as_float(u[j] & 0xffff0000u);
            }
        }
        for (; k + 8 <= kmax; k += 8) {
            unsigned int u[8];
            #pragma unroll
            for (int j = 0; j < 8; j++) {
                int s = __shfl(rec, k + j, 64);
                u[j] = Hb[(size_t)s * 64 + lane];
            }
            #pragma unroll
            for (int j = 0; j < 8; j++) {
                acc.x += __uint_as_float(u[j] << 16);
                acc.y += __uint_as_float(u[j] & 0xffff0000u);
            }
        }
        for (; k < kmax; k++) {
            int s0 = __shfl(rec, k, 64);
            unsigned int u0 = Hb[(size_t)s0 * 64 + lane];
            acc.x += __uint_as_float(u0 << 16);
            acc.y += __uint_as_float(u0 & 0xffff0000u);
        }
    }
    float dvv = dinv[v];
    acc.x *= dvv;
    acc.y *= dvv;
    if (BIAS_RELU) {
        float2 bb = ((const float2*)bias)[lane];
        acc.x = fmaxf(acc.x + bb.x, 0.f);
        acc.y = fmaxf(acc.y + bb.y, 0.f);
    }
    Out[v * 64 + lane] = pack_bf16x2(acc.x, acc.y);
}

// ---------------- segmented mean-pool (batch sorted), bf16 input ----------------
// 64 threads/block; thread d owns feats {2d, 2d+1}; one uint per node per thread.
__global__ void pool_kernel(const unsigned int* __restrict__ Hb, const int* __restrict__ batch,
                            float* __restrict__ gsum, float* __restrict__ gcnt, int n) {
    __shared__ int bl[128];
    int d = threadIdx.x;     // 0..63
    int base = blockIdx.x * 128;
    int cnt_here = min(128, n - base);
    if (cnt_here <= 0) return;
    for (int i = d; i < cnt_here; i += 64) bl[i] = batch[base + i];
    __syncthreads();
    float a0 = 0.f, a1 = 0.f;
    int cg = -1, c = 0;
    for (int i = 0; i < cnt_here; i++) {
        int g = bl[i];
        if (g != cg) {
            if (cg >= 0) {
                atomicAdd(&gsum[cg * DF + 2 * d], a0);
                atomicAdd(&gsum[cg * DF + 2 * d + 1], a1);
                if (d == 0) atomicAdd(&gcnt[cg], (float)c);
            }
            a0 = 0.f; a1 = 0.f; c = 0; cg = g;
        }
        unsigned int u = Hb[(size_t)(base + i) * 64 + d];
        a0 += __uint_as_float(u << 16);
        a1 += __uint_as_float(u & 0xffff0000u);
        c++;
    }
    if (cg >= 0) {
        atomicAdd(&gsum[cg * DF + 2 * d], a0);
        atomicAdd(&gsum[cg * DF + 2 * d + 1], a1);
        if (d == 0) atomicAdd(&gcnt[cg], (float)c);
    }
}

// ---------------- final: out[g] = dot(gsum[g]/cnt + b2, Wm) + bm ----------------
__global__ void final_kernel(const float* __restrict__ gsum, const float* __restrict__ gcnt,
                             const float* __restrict__ b2, const float* __restrict__ Wm,
                             const float* __restrict__ bm, float* __restrict__ out) {
    __shared__ float red[2];
    int g = blockIdx.x, d = threadIdx.x;
    float cnt = fmaxf(gcnt[g], 1.0f);
    float v = (gsum[g * DF + d] / cnt + b2[d]) * Wm[d];
    for (int off = 32; off > 0; off >>= 1) v += __shfl_down(v, off, 64);
    if ((d & 63) == 0) red[d >> 6] = v;
    __syncthreads();
    if (d == 0) out[g] = red[0] + red[1] + bm[0];
}

extern "C" void kernel_launch(void* const* d_in, const int* in_sizes, int n_in,
                              void* d_out, int out_size, void* d_ws, size_t ws_size,
                              hipStream_t stream) {
    const float* x   = (const float*)d_in[0];
    const int*   ei  = (const int*)d_in[1];   // [2, E] flat: first E = src, next E = dst
    const int*   bat = (const int*)d_in[2];
    const float* W1  = (const float*)d_in[3];
    const float* b1  = (const float*)d_in[4];
    const float* W2  = (const float*)d_in[5];
    const float* b2  = (const float*)d_in[6];
    const float* Wm  = (const float*)d_in[7];
    const float* bm  = (const float*)d_in[8];
    float* out = (float*)d_out;

    const int N = NNODES, E = NEDGES, G = NGRAPH;
    const int* src = ei;
    const int* dst = ei + E;

    // workspace carve
    char* base = (char*)d_ws;
    size_t o = 0;
    auto alloc = [&](size_t bytes) { size_t p = o; o = (o + bytes + 255) & ~(size_t)255; return p; };
    int*   deg    = (int*)(base + alloc((size_t)N * 4));
    int*   offs   = (int*)(base + alloc((size_t)(N + 1) * 4));
    float* dinv   = (float*)(base + alloc((size_t)N * 4));
    int*   psum   = (int*)(base + alloc((size_t)NB_SCAN * 4));
    int*   cnt    = (int*)(base + alloc((size_t)NBLK2 * NBUCK * 4));
    int*   bstart = (int*)(base + alloc((size_t)NBLK2 * NBUCK * 4));
    int*   btot   = (int*)(base + alloc((size_t)NBUCK * 4));
    int*   segoff = (int*)(base + alloc((size_t)(NBUCK + 1) * 4));
    unsigned int* stage = (unsigned int*)(base + alloc((size_t)E * 4));
    int*   csrc   = (int*)(base + alloc((size_t)(E + N) * 4));
    unsigned int* bufH  = (unsigned int*)(base + alloc((size_t)N * DF * 2));  // bf16 H (dinv-scaled)
    unsigned int* bufA16 = (unsigned int*)(base + alloc((size_t)N * DF * 2)); // bf16 agg outputs
    float* gsum   = (float*)(base + alloc((size_t)G * DF * 4));               // 131072 B (256-mult)
    float* gcnt   = (float*)(base + alloc((size_t)G * 4));                    // adjacent to gsum
    unsigned short* wh1 = (unsigned short*)(base + alloc(2048 * 16));
    unsigned short* wl1 = (unsigned short*)(base + alloc(2048 * 16));
    unsigned short* wh2 = (unsigned short*)(base + alloc(2048 * 16));
    unsigned short* wl2 = (unsigned short*)(base + alloc(2048 * 16));
    (void)ws_size;

    // gsum + gcnt are adjacent (gsum size is a multiple of 256) -> single memset
    hipMemsetAsync(gsum, 0, (size_t)G * DF * 4 + (size_t)G * 4, stream);

    // atomic-free binned CSR build
    hist2<<<NBLK2, 1024, 0, stream>>>(dst, cnt, E);
    bscan1<<<NBUCK, 64, 0, stream>>>(cnt, bstart, btot);
    segscan2<<<1, 256, 0, stream>>>(btot, segoff);
    scatter2<<<NBLK2, 1024, 0, stream>>>(src, dst, bstart, segoff, stage, E);
    bucket_deg<<<NBUCK, 256, 0, stream>>>(stage, segoff, deg, N);
    scan1_kernel<<<NB_SCAN, 256, 0, stream>>>(deg, psum, dinv, N);
    scan2_kernel<<<1, 64, 0, stream>>>(psum, offs, NB_SCAN, N);
    scan3_kernel<<<NB_SCAN, 256, 0, stream>>>(deg, psum, offs, N);
    bucket_place<<<NBUCK, 256, 0, stream>>>(stage, segoff, offs, csrc, N);

    // W prep (both layers, one launch)
    wprep2<<<16, 256, 0, stream>>>(W1, W2, wh1, wl1, wh2, wl2);

    // layer 1: bufH = bf16(dinv .* (x @ W1)) ; bufA16 = bf16(relu(dinv[v]*sum + b1))
    gemm_mfma<0><<<(N + 63) / 64, 256, 0, stream>>>(x, wh1, wl1, dinv, bufH, N);
    agg_kernel<1><<<N / 4, 256, 0, stream>>>(offs, csrc, dinv, bufH, b1, bufA16);

    // layer 2: bufH = bf16(dinv .* (bufA16 @ W2)) ; bufA16 = bf16(dinv[v]*sum)
    gemm_mfma<1><<<(N + 63) / 64, 256, 0, stream>>>(bufA16, wh2, wl2, dinv, bufH, N);
    agg_kernel<0><<<N / 4, 256, 0, stream>>>(offs, csrc, dinv, bufH, nullptr, bufA16);

    // pool (bf16 input) + final
    pool_kernel<<<(N + 127) / 128, 64, 0, stream>>>(bufA16, bat, gsum, gcnt, N);
    final_kernel<<<G, 128, 0, stream>>>(gsum, gcnt, b2, Wm, bm, out);
}

// Round 17
// 264.815 us; speedup vs baseline: 1.1960x; 1.0417x over previous
//
#include <hip/hip_runtime.h>
#include <hip/hip_bf16.h>

#define NNODES 100000
#define NEDGES 1600000
#define DF 128
#define NGRAPH 256

#define BUCKET_SHIFT 7
#define BUCKET_NODES 128
#define NBUCK ((NNODES + BUCKET_NODES - 1) / BUCKET_NODES)   // 782
#define SCHUNK 8192
#define NBLK2 ((NEDGES + SCHUNK - 1) / SCHUNK)               // 196

typedef __attribute__((ext_vector_type(8))) short short8;
typedef __attribute__((ext_vector_type(4))) float f32x4;

// ---------------- pass A: per-block bucket histogram -> cnt[blk][NBUCK] (no atomics) --
__global__ __launch_bounds__(1024) void hist2(const int* __restrict__ dst,
                                              int* __restrict__ cnt, int E) {
    __shared__ int h[NBUCK];
    for (int i = threadIdx.x; i < NBUCK; i += 1024) h[i] = 0;
    __syncthreads();
    int base = blockIdx.x * SCHUNK;
    #pragma unroll
    for (int j = 0; j < 8; j++) {
        int e = base + threadIdx.x + j * 1024;
        if (e < E) atomicAdd(&h[dst[e] >> BUCKET_SHIFT], 1);
    }
    __syncthreads();
    for (int i = threadIdx.x; i < NBUCK; i += 1024)
        cnt[blockIdx.x * NBUCK + i] = h[i];
}

// ---------------- per-bucket exclusive scan over blocks -> bstart[blk][b], btot[b] ----
__global__ void bscan1(const int* __restrict__ cnt, int* __restrict__ bstart,
                       int* __restrict__ btot) {
    int b = blockIdx.x;      // one 64-thread wave per bucket
    int l = threadIdx.x;
    int vals[4];
    int s = 0;
    #pragma unroll
    for (int i = 0; i < 4; i++) {
        int blk = l * 4 + i;
        vals[i] = (blk < NBLK2) ? cnt[blk * NBUCK + b] : 0;
        s += vals[i];
    }
    int pre = s;
    for (int off = 1; off < 64; off <<= 1) {
        int t = __shfl_up(pre, off, 64);
        if (l >= off) pre += t;
    }
    pre -= s;  // exclusive prefix of this lane's group
    int run = pre;
    #pragma unroll
    for (int i = 0; i < 4; i++) {
        int blk = l * 4 + i;
        if (blk < NBLK2) { bstart[blk * NBUCK + b] = run; run += vals[i]; }
    }
    if (l == 63) btot[b] = pre + s;
}

// ---------------- scan bucket totals -> segoff[0..NBUCK] ----------------
__global__ void segscan2(const int* __restrict__ btot, int* __restrict__ segoff) {
    __shared__ int lds[256];
    int t = threadIdx.x;
    int b0 = t * 4;
    int v[4];
    int s = 0;
    #pragma unroll
    for (int i = 0; i < 4; i++) { int b = b0 + i; v[i] = (b < NBUCK) ? btot[b] : 0; s += v[i]; }
    lds[t] = s;
    __syncthreads();
    for (int off = 1; off < 256; off <<= 1) {
        int x = lds[t];
        int a = (t >= off) ? lds[t - off] : 0;
        __syncthreads();
        lds[t] = x + a;
        __syncthreads();
    }
    int run = lds[t] - s;
    #pragma unroll
    for (int i = 0; i < 4; i++) {
        int b = b0 + i;
        if (b < NBUCK) { segoff[b] = run; run += v[i]; }
    }
    if (t == 255) segoff[NBUCK] = lds[255];
}

// ---------------- pass B: LDS counting-sort scatter, burst coalesced writes ----------
__global__ __launch_bounds__(1024) void scatter2(const int* __restrict__ src,
                                                 const int* __restrict__ dst,
                                                 const int* __restrict__ bstart,
                                                 const int* __restrict__ segoff,
                                                 unsigned int* __restrict__ stage, int E) {
    __shared__ unsigned int rec[SCHUNK];     // 32 KB sorted records
    __shared__ unsigned short bid[SCHUNK];   // 16 KB bucket id per slot
    __shared__ int hs[1024];                 // per-bucket counts
    __shared__ int wsum[16];
    __shared__ int cur[NBUCK];               // local cursors
    __shared__ int delta[NBUCK];             // global dest - local slot
    __shared__ int nrec_s;
    int tid = threadIdx.x, lane = tid & 63, wid = tid >> 6;
    int base = blockIdx.x * SCHUNK;
    hs[tid] = 0;
    __syncthreads();
    int myd[8], mys[8];
    #pragma unroll
    for (int j = 0; j < 8; j++) {
        int e = base + tid + j * 1024;
        if (e < E) {
            myd[j] = dst[e];
            mys[j] = src[e];
            atomicAdd(&hs[myd[j] >> BUCKET_SHIFT], 1);
        } else myd[j] = -1;
    }
    __syncthreads();
    int cnt_t = hs[tid];
    // wave-level inclusive scan (no barriers), then cross-wave via LDS
    int pre = cnt_t;
    for (int off = 1; off < 64; off <<= 1) {
        int t = __shfl_up(pre, off, 64);
        if (lane >= off) pre += t;
    }
    if (lane == 63) wsum[wid] = pre;
    __syncthreads();
    if (tid == 0) {
        int r = 0;
        #pragma unroll
        for (int i = 0; i < 16; i++) { int t = wsum[i]; wsum[i] = r; r += t; }
        nrec_s = r;
    }
    __syncthreads();
    int excl = pre - cnt_t + wsum[wid];
    if (tid < NBUCK) {
        cur[tid] = excl;
        delta[tid] = segoff[tid] + bstart[blockIdx.x * NBUCK + tid] - excl;
    }
    __syncthreads();
    #pragma unroll
    for (int j = 0; j < 8; j++) {
        if (myd[j] >= 0) {
            int b = myd[j] >> BUCKET_SHIFT;
            int p = atomicAdd(&cur[b], 1);
            rec[p] = (unsigned int)mys[j] | (((unsigned int)myd[j] & 127u) << 17);
            bid[p] = (unsigned short)b;
        }
    }
    __syncthreads();
    int nrec = nrec_s;
    for (int i = tid; i < nrec; i += 1024)
        stage[delta[bid[i]] + i] = rec[i];
}

// ---------------- fused pass C: per-bucket histogram + local scan -> offs, dinv,
// self-loop records, and edge placement — one kernel, one cold stage read.
// Region for bucket b starts at segoff[b] + b*128 (each node adds 1 self-loop).
__global__ void bucket_build(const unsigned int* __restrict__ stage,
                             const int* __restrict__ segoff,
                             int* __restrict__ offs, float* __restrict__ dinv,
                             int* __restrict__ csrc, int n) {
    __shared__ int h[BUCKET_NODES];
    __shared__ int loc[BUCKET_NODES];
    __shared__ int cur[BUCKET_NODES];
    int b = blockIdx.x;
    int tid = threadIdx.x;
    if (tid < BUCKET_NODES) h[tid] = 0;
    __syncthreads();
    int s0 = segoff[b], s1 = segoff[b + 1];
    for (int i = s0 + tid; i < s1; i += 256)
        atomicAdd(&h[(stage[i] >> 17) & 127u], 1);
    __syncthreads();
    // inclusive ladder scan over (h[i]+1), 128 entries
    if (tid < BUCKET_NODES) loc[tid] = h[tid] + 1;
    __syncthreads();
    for (int off = 1; off < BUCKET_NODES; off <<= 1) {
        int x = 0, a = 0;
        if (tid < BUCKET_NODES) {
            x = loc[tid];
            if (tid >= off) a = loc[tid - off];
        }
        __syncthreads();
        if (tid < BUCKET_NODES) loc[tid] = x + a;
        __syncthreads();
    }
    int R = s0 + b * BUCKET_NODES;
    int v = b * BUCKET_NODES + tid;
    if (tid < BUCKET_NODES && v < n) {
        int excl = loc[tid] - (h[tid] + 1);   // exclusive prefix
        int o = R + excl;
        offs[v] = o;
        dinv[v] = rsqrtf((float)h[tid] + 1.0f);
        csrc[o] = v;                          // slot 0 = self loop
        cur[tid] = o + 1;
        if (v == n - 1) offs[n] = o + h[tid] + 1;
    }
    __syncthreads();
    // second pass over the (now L2-hot) segment: place edge records
    for (int i = s0 + tid; i < s1; i += 256) {
        unsigned int r = stage[i];
        int pos = atomicAdd(&cur[(r >> 17) & 127u], 1);
        csrc[pos] = (int)(r & 0x1ffffu);
    }
}

// RNE pack: two f32 -> bf16x2 (lo = a, hi = b)
__device__ __forceinline__ unsigned int pack_bf16x2(float a, float b) {
    unsigned int ua = __float_as_uint(a);
    unsigned int ub = __float_as_uint(b);
    ua += 0x7fffu + ((ua >> 16) & 1u);
    ub += 0x7fffu + ((ub >> 16) & 1u);
    return (ua >> 16) | (ub & 0xffff0000u);
}

// split f32 -> (hi bf16, lo bf16): w ~= hi + lo, error ~2^-17 relative
__device__ __forceinline__ void split_bf16(float w, unsigned short& h, unsigned short& l) {
    unsigned int uw = __float_as_uint(w);
    unsigned int hb = uw + 0x7fffu + ((uw >> 16) & 1u);
    h = (unsigned short)(hb >> 16);
    float rem = w - __uint_as_float((unsigned int)h << 16);
    unsigned int ur = __float_as_uint(rem);
    unsigned int lb = ur + 0x7fffu + ((ur >> 16) & 1u);
    l = (unsigned short)(lb >> 16);
}

// ---------------- W prep (both weights in one launch): frag-major split-bf16 ----------
__global__ void wprep2(const float* __restrict__ W1, const float* __restrict__ W2,
                       unsigned short* __restrict__ Wh1, unsigned short* __restrict__ Wl1,
                       unsigned short* __restrict__ Wh2, unsigned short* __restrict__ Wl2) {
    int gidx = blockIdx.x * 256 + threadIdx.x;  // 0..4095
    int which = gidx >> 11;
    int id = gidx & 2047;
    const float* W = which ? W2 : W1;
    unsigned short* Wh = which ? Wh2 : Wh1;
    unsigned short* Wl = which ? Wl2 : Wl1;
    int lane = id & 63, tq = id >> 6;
    int t = tq >> 2, q = tq & 3;
    int n = 16 * t + (lane & 15);
    int kbase = 32 * q + 8 * (lane >> 4);
    unsigned short h[8], l[8];
    #pragma unroll
    for (int i = 0; i < 8; i++) {
        split_bf16(W[(kbase + i) * DF + n], h[i], l[i]);
    }
    uint4 hv, lv;
    hv.x = h[0] | ((unsigned int)h[1] << 16); hv.y = h[2] | ((unsigned int)h[3] << 16);
    hv.z = h[4] | ((unsigned int)h[5] << 16); hv.w = h[6] | ((unsigned int)h[7] << 16);
    lv.x = l[0] | ((unsigned int)l[1] << 16); lv.y = l[2] | ((unsigned int)l[3] << 16);
    lv.z = l[4] | ((unsigned int)l[5] << 16); lv.w = l[6] | ((unsigned int)l[7] << 16);
    ((uint4*)Wh)[id] = hv;
    ((uint4*)Wl)[id] = lv;
}

// ---------------- MFMA GEMM: C_bf16[n,128] = dinv[n] * (A[n,128] @ W[128,128]) --------
template <int ABF16>
__global__ void gemm_mfma(const void* __restrict__ Ap, const unsigned short* __restrict__ Wh,
                          const unsigned short* __restrict__ Wl, const float* __restrict__ dinv,
                          unsigned int* __restrict__ C, int nrows) {
    int tid = threadIdx.x;
    int wv = tid >> 6, lane = tid & 63;
    int c16 = lane & 15, g = lane >> 4;
    int row = blockIdx.x * 64 + wv * 16 + c16;
    int rowc = min(row, nrows - 1);
    const short8* Wh8 = (const short8*)Wh;
    const short8* Wl8 = (const short8*)Wl;
    f32x4 acc[8];
    #pragma unroll
    for (int t = 0; t < 8; t++) acc[t] = (f32x4){0.f, 0.f, 0.f, 0.f};
    #pragma unroll
    for (int q = 0; q < 4; q++) {
        short8 ah, al;
        if (ABF16) {
            ah = ((const short8*)Ap)[(size_t)rowc * 16 + q * 4 + g];
        } else {
            const float4* A4 = (const float4*)Ap;
            float4 a0 = A4[(size_t)rowc * 32 + q * 8 + g * 2];
            float4 a1 = A4[(size_t)rowc * 32 + q * 8 + g * 2 + 1];
            float av[8] = {a0.x, a0.y, a0.z, a0.w, a1.x, a1.y, a1.z, a1.w};
            #pragma unroll
            for (int i = 0; i < 8; i++) {
                unsigned short hs, ls;
                split_bf16(av[i], hs, ls);
                ah[i] = (short)hs;
                al[i] = (short)ls;
            }
        }
        #pragma unroll
        for (int t = 0; t < 8; t++) {
            short8 wh = Wh8[(t * 4 + q) * 64 + lane];
            short8 wl = Wl8[(t * 4 + q) * 64 + lane];
            acc[t] = __builtin_amdgcn_mfma_f32_16x16x32_bf16(wh, ah, acc[t], 0, 0, 0);
            if (!ABF16) acc[t] = __builtin_amdgcn_mfma_f32_16x16x32_bf16(wh, al, acc[t], 0, 0, 0);
            acc[t] = __builtin_amdgcn_mfma_f32_16x16x32_bf16(wl, ah, acc[t], 0, 0, 0);
        }
    }
    if (row < nrows) {
        float dvr = dinv[row];
        uint2* C2 = (uint2*)C;
        #pragma unroll
        for (int t = 0; t < 8; t++) {
            uint2 w;
            w.x = pack_bf16x2(acc[t][0] * dvr, acc[t][1] * dvr);
            w.y = pack_bf16x2(acc[t][2] * dvr, acc[t][3] * dvr);
            C2[(size_t)row * 32 + t * 4 + g] = w;
        }
    }
}

// ---------------- CSR aggregation (unroll 16): out[v] = epi(dinv[v]*sum), bf16 out ----
template <int BIAS_RELU>
__global__ void agg_kernel(const int* __restrict__ roff, const int* __restrict__ csrc,
                           const float* __restrict__ dinv, const unsigned int* __restrict__ Hb,
                           const float* __restrict__ bias, unsigned int* __restrict__ Out) {
    int tid = threadIdx.x;
    int wv = tid >> 6, lane = tid & 63;
    size_t v = (size_t)blockIdx.x * 4 + wv;
    int b = roff[v], e = roff[v + 1];
    float2 acc = {0.f, 0.f};
    for (int base = b; base < e; base += 64) {
        int idx = base + lane;
        if (idx >= e) idx = e - 1;       // clamped dup, never consumed
        int rec = csrc[idx];             // one coalesced 256B record load
        int kmax = min(64, e - base);
        int k = 0;
        for (; k + 16 <= kmax; k += 16) {
            unsigned int u[16];
            #pragma unroll
            for (int j = 0; j < 16; j++) {
                int s = __shfl(rec, k + j, 64);
                u[j] = Hb[(size_t)s * 64 + lane];      // 256B row gather
            }
            #pragma unroll
            for (int j = 0; j < 16; j++) {
                acc.x += __uint_as_float(u[j] << 16);
                acc.y += __uint_as_float(u[j] & 0xffff0000u);
            }
        }
        for (; k + 8 <= kmax; k += 8) {
            unsigned int u[8];
            #pragma unroll
            for (int j = 0; j < 8; j++) {
                int s = __shfl(rec, k + j, 64);
                u[j] = Hb[(size_t)s * 64 + lane];
            }
            #pragma unroll
            for (int j = 0; j < 8; j++) {
                acc.x += __uint_as_float(u[j] << 16);
                acc.y += __uint_as_float(u[j] & 0xffff0000u);
            }
        }
        for (; k < kmax; k++) {
            int s0 = __shfl(rec, k, 64);
            unsigned int u0 = Hb[(size_t)s0 * 64 + lane];
            acc.x += __uint_as_float(u0 << 16);
            acc.y += __uint_as_float(u0 & 0xffff0000u);
        }
    }
    float dvv = dinv[v];
    acc.x *= dvv;
    acc.y *= dvv;
    if (BIAS_RELU) {
        float2 bb = ((const float2*)bias)[lane];
        acc.x = fmaxf(acc.x + bb.x, 0.f);
        acc.y = fmaxf(acc.y + bb.y, 0.f);
    }
    Out[v * 64 + lane] = pack_bf16x2(acc.x, acc.y);
}

// ---------------- segmented mean-pool (batch sorted), bf16 input ----------------
__global__ void pool_kernel(const unsigned int* __restrict__ Hb, const int* __restrict__ batch,
                            float* __restrict__ gsum, float* __restrict__ gcnt, int n) {
    __shared__ int bl[128];
    int d = threadIdx.x;     // 0..63
    int base = blockIdx.x * 128;
    int cnt_here = min(128, n - base);
    if (cnt_here <= 0) return;
    for (int i = d; i < cnt_here; i += 64) bl[i] = batch[base + i];
    __syncthreads();
    float a0 = 0.f, a1 = 0.f;
    int cg = -1, c = 0;
    for (int i = 0; i < cnt_here; i++) {
        int g = bl[i];
        if (g != cg) {
            if (cg >= 0) {
                atomicAdd(&gsum[cg * DF + 2 * d], a0);
                atomicAdd(&gsum[cg * DF + 2 * d + 1], a1);
                if (d == 0) atomicAdd(&gcnt[cg], (float)c);
            }
            a0 = 0.f; a1 = 0.f; c = 0; cg = g;
        }
        unsigned int u = Hb[(size_t)(base + i) * 64 + d];
        a0 += __uint_as_float(u << 16);
        a1 += __uint_as_float(u & 0xffff0000u);
        c++;
    }
    if (cg >= 0) {
        atomicAdd(&gsum[cg * DF + 2 * d], a0);
        atomicAdd(&gsum[cg * DF + 2 * d + 1], a1);
        if (d == 0) atomicAdd(&gcnt[cg], (float)c);
    }
}

// ---------------- final: out[g] = dot(gsum[g]/cnt + b2, Wm) + bm ----------------
__global__ void final_kernel(const float* __restrict__ gsum, const float* __restrict__ gcnt,
                             const float* __restrict__ b2, const float* __restrict__ Wm,
                             const float* __restrict__ bm, float* __restrict__ out) {
    __shared__ float red[2];
    int g = blockIdx.x, d = threadIdx.x;
    float cnt = fmaxf(gcnt[g], 1.0f);
    float v = (gsum[g * DF + d] / cnt + b2[d]) * Wm[d];
    for (int off = 32; off > 0; off >>= 1) v += __shfl_down(v, off, 64);
    if ((d & 63) == 0) red[d >> 6] = v;
    __syncthreads();
    if (d == 0) out[g] = red[0] + red[1] + bm[0];
}

extern "C" void kernel_launch(void* const* d_in, const int* in_sizes, int n_in,
                              void* d_out, int out_size, void* d_ws, size_t ws_size,
                              hipStream_t stream) {
    const float* x   = (const float*)d_in[0];
    const int*   ei  = (const int*)d_in[1];   // [2, E] flat: first E = src, next E = dst
    const int*   bat = (const int*)d_in[2];
    const float* W1  = (const float*)d_in[3];
    const float* b1  = (const float*)d_in[4];
    const float* W2  = (const float*)d_in[5];
    const float* b2  = (const float*)d_in[6];
    const float* Wm  = (const float*)d_in[7];
    const float* bm  = (const float*)d_in[8];
    float* out = (float*)d_out;

    const int N = NNODES, E = NEDGES, G = NGRAPH;
    const int* src = ei;
    const int* dst = ei + E;

    // workspace carve
    char* base = (char*)d_ws;
    size_t o = 0;
    auto alloc = [&](size_t bytes) { size_t p = o; o = (o + bytes + 255) & ~(size_t)255; return p; };
    int*   offs   = (int*)(base + alloc((size_t)(N + 1) * 4));
    float* dinv   = (float*)(base + alloc((size_t)N * 4));
    int*   cnt    = (int*)(base + alloc((size_t)NBLK2 * NBUCK * 4));
    int*   bstart = (int*)(base + alloc((size_t)NBLK2 * NBUCK * 4));
    int*   btot   = (int*)(base + alloc((size_t)NBUCK * 4));
    int*   segoff = (int*)(base + alloc((size_t)(NBUCK + 1) * 4));
    unsigned int* stage = (unsigned int*)(base + alloc((size_t)E * 4));
    int*   csrc   = (int*)(base + alloc((size_t)(E + N) * 4));
    unsigned int* bufH  = (unsigned int*)(base + alloc((size_t)N * DF * 2));  // bf16 H (dinv-scaled)
    unsigned int* bufA16 = (unsigned int*)(base + alloc((size_t)N * DF * 2)); // bf16 agg outputs
    float* gsum   = (float*)(base + alloc((size_t)G * DF * 4));               // 131072 B (256-mult)
    float* gcnt   = (float*)(base + alloc((size_t)G * 4));                    // adjacent to gsum
    unsigned short* wh1 = (unsigned short*)(base + alloc(2048 * 16));
    unsigned short* wl1 = (unsigned short*)(base + alloc(2048 * 16));
    unsigned short* wh2 = (unsigned short*)(base + alloc(2048 * 16));
    unsigned short* wl2 = (unsigned short*)(base + alloc(2048 * 16));
    (void)ws_size;

    // gsum + gcnt are adjacent (gsum size is a multiple of 256) -> single memset
    hipMemsetAsync(gsum, 0, (size_t)G * DF * 4 + (size_t)G * 4, stream);

    // atomic-free binned CSR build (fused: one kernel for deg+scan+place)
    hist2<<<NBLK2, 1024, 0, stream>>>(dst, cnt, E);
    bscan1<<<NBUCK, 64, 0, stream>>>(cnt, bstart, btot);
    segscan2<<<1, 256, 0, stream>>>(btot, segoff);
    scatter2<<<NBLK2, 1024, 0, stream>>>(src, dst, bstart, segoff, stage, E);
    bucket_build<<<NBUCK, 256, 0, stream>>>(stage, segoff, offs, dinv, csrc, N);

    // W prep (both layers, one launch)
    wprep2<<<16, 256, 0, stream>>>(W1, W2, wh1, wl1, wh2, wl2);

    // layer 1: bufH = bf16(dinv .* (x @ W1)) ; bufA16 = bf16(relu(dinv[v]*sum + b1))
    gemm_mfma<0><<<(N + 63) / 64, 256, 0, stream>>>(x, wh1, wl1, dinv, bufH, N);
    agg_kernel<1><<<N / 4, 256, 0, stream>>>(offs, csrc, dinv, bufH, b1, bufA16);

    // layer 2: bufH = bf16(dinv .* (bufA16 @ W2)) ; bufA16 = bf16(dinv[v]*sum)
    gemm_mfma<1><<<(N + 63) / 64, 256, 0, stream>>>(bufA16, wh2, wl2, dinv, bufH, N);
    agg_kernel<0><<<N / 4, 256, 0, stream>>>(offs, csrc, dinv, bufH, nullptr, bufA16);

    // pool (bf16 input) + final
    pool_kernel<<<(N + 127) / 128, 64, 0, stream>>>(bufA16, bat, gsum, gcnt, N);
    final_kernel<<<G, 128, 0, stream>>>(gsum, gcnt, b2, Wm, bm, out);
}